// Round 4
// baseline (808.992 us; speedup 1.0000x reference)
//
#include <hip/hip_runtime.h>

typedef float f4 __attribute__((ext_vector_type(4)));
typedef __attribute__((ext_vector_type(4))) float f32x4;
typedef __attribute__((ext_vector_type(8))) short bf8;

__device__ __forceinline__ ushort f2bf(float f) {
    union { float f; unsigned u; } v; v.f = f;
    return (ushort)((v.u + 0x7FFFu + ((v.u >> 16) & 1u)) >> 16);
}
__device__ __forceinline__ float bf2f(unsigned hu16) {
    union { unsigned u; float f; } v; v.u = hu16 << 16;
    return v.f;
}
__device__ __forceinline__ void split2(float v, ushort& hi, ushort& lo) {
    hi = f2bf(v);
    lo = f2bf(v - bf2f((unsigned)hi));
}

__global__ __launch_bounds__(256, 3)
void avif_mfma3(const float* __restrict__ x, const float* __restrict__ twm,
                const float* __restrict__ w1, const float* __restrict__ b1,
                const float* __restrict__ w2, const float* __restrict__ b2,
                float* __restrict__ out)
{
    // XOR-swizzled planes (granule = 8 ushorts = 16B):
    // element (px, c) -> row px, ushort index ((c>>3)^(px&7))*8 + (c&7)
    __shared__ ushort ysh[128][64];   // Y hi
    __shared__ ushort ysl[128][64];   // Y lo
    __shared__ ushort hsh[128][64];   // H hi only (48 KB total -> 3 blocks/CU)

    const int t = threadIdx.x;
    const int bid = blockIdx.x;
    // XCD-friendly decode
    const int b3 = (bid >> 3) & 1;
    const int u  = ((bid >> 4) << 3) | (bid & 7);
    const int wt = ((u & 15) << 1) | b3;   // 0..31
    const int hb = (u >> 4) & 63;          // 0..63
    const int b  = u >> 10;                // 0..3

    const int wv   = t >> 6;
    const int lane = t & 63;
    const int li   = lane & 15;
    const int lg   = lane >> 4;
    const int l7   = li & 7;

    // ---- phase 1: all 256 threads; lane pairs (2m,2m+1) share one (c,blk) ----
    {
        const int pid = t >> 1;          // 0..127
        const int h2  = t & 1;           // M-row half / Y-col half
        const int c   = pid & 63, blk = pid >> 6;
        const int r0  = 4 * h2, r1 = 4 - r0;
        const float* xB = x + ((size_t)(b * 64 + c) * 512 + hb * 8 + r0) * 512
                            + wt * 16 + blk * 8;
        float P[4][8];
#pragma unroll
        for (int i = 0; i < 4; ++i) {
            f4 a = *(const f4*)(xB + i * 512);
            f4 d = *(const f4*)(xB + i * 512 + 4);
#pragma unroll
            for (int q = 0; q < 4; ++q) { P[i][q] = a[q]; P[i][4 + q] = d[q]; }
        }
        float T[8][8];
        const f4* tv = (const f4*)(twm + c * 64);
#pragma unroll
        for (int r = 0; r < 8; ++r) {
            f4 a = tv[2 * r], d = tv[2 * r + 1];
#pragma unroll
            for (int q = 0; q < 4; ++q) { T[r][q] = a[q]; T[r][4 + q] = d[q]; }
        }
        // my 4 rows of M = P * T^T
        float M[4][8];
#pragma unroll
        for (int i = 0; i < 4; ++i)
#pragma unroll
            for (int q = 0; q < 8; ++q) {
                float s = 0.f;
#pragma unroll
                for (int j2 = 0; j2 < 8; ++j2) s = fmaf(P[i][j2], T[q][j2], s);
                M[i][q] = s;
            }
        // exchange with partner lane (other 4 rows)
        float MO[4][8];
#pragma unroll
        for (int i = 0; i < 4; ++i)
#pragma unroll
            for (int q = 0; q < 8; ++q) MO[i][q] = __shfl_xor(M[i][q], 1);
        // my 4 COLUMNS of Y = T * M  (q = r0..r0+3); even/odd lanes hit
        // disjoint bank halves on the swizzled b16 stores.
        const int cg = c >> 3, c7 = c & 7;
#pragma unroll
        for (int p = 0; p < 8; ++p) {
#pragma unroll
            for (int qq = 0; qq < 4; ++qq) {
                const int q = r0 + qq;
                float s = 0.f;
#pragma unroll
                for (int i = 0; i < 4; ++i) {
                    s = fmaf(T[p][r0 + i], M[i][q], s);
                    s = fmaf(T[p][r1 + i], MO[i][q], s);
                }
                ushort hi, lo; split2(s, hi, lo);
                const int px  = p * 16 + blk * 8 + q;
                const int idx = ((cg ^ q) << 3) | c7;
                ysh[px][idx] = hi;
                ysl[px][idx] = lo;
            }
        }
    }

    // ---- W fragments (hi+lo) in registers ----
    bf8 w1h[2], w1l[2], w2h[2], w2l[2];
    {
        const float* p1 = w1 + (16 * wv + li) * 64 + lg * 8;
        const float* p2 = w2 + (16 * wv + li) * 64 + lg * 8;
#pragma unroll
        for (int kk = 0; kk < 2; ++kk) {
            f4 a = *(const f4*)(p1 + kk * 32);
            f4 d = *(const f4*)(p1 + kk * 32 + 4);
            bf8 fh, fl; ushort hi, lo;
#pragma unroll
            for (int q = 0; q < 4; ++q) {
                split2(a[q], hi, lo); fh[q] = (short)hi; fl[q] = (short)lo;
                split2(d[q], hi, lo); fh[4 + q] = (short)hi; fl[4 + q] = (short)lo;
            }
            w1h[kk] = fh; w1l[kk] = fl;
            a = *(const f4*)(p2 + kk * 32);
            d = *(const f4*)(p2 + kk * 32 + 4);
#pragma unroll
            for (int q = 0; q < 4; ++q) {
                split2(a[q], hi, lo); fh[q] = (short)hi; fl[q] = (short)lo;
                split2(d[q], hi, lo); fh[4 + q] = (short)hi; fl[4 + q] = (short)lo;
            }
            w2h[kk] = fh; w2l[kk] = fl;
        }
    }
    const int o0 = 16 * wv + 4 * lg;
    const f4 b1v = *(const f4*)(b1 + o0);
    const f4 b2v = *(const f4*)(b2 + o0);
    const int sg0 = ((lg)     ^ l7) << 3;
    const int sg1 = ((4 + lg) ^ l7) << 3;
    const int go  = o0 >> 3, co = 4 * (lg & 1);

    __syncthreads();

    // ---- GEMM1: H = relu(W1 * Y + b1), split x split (3 MFMA per K=32) ----
    f32x4 acc[8];
#pragma unroll
    for (int j = 0; j < 8; ++j) acc[j] = (f32x4){0.f, 0.f, 0.f, 0.f};
#pragma unroll
    for (int j = 0; j < 8; ++j) {
        const int row = 16 * j + li;
        bf8 bh0 = *(const bf8*)&ysh[row][sg0];
        bf8 bl0 = *(const bf8*)&ysl[row][sg0];
        bf8 bh1 = *(const bf8*)&ysh[row][sg1];
        bf8 bl1 = *(const bf8*)&ysl[row][sg1];
        acc[j] = __builtin_amdgcn_mfma_f32_16x16x32_bf16(w1h[0], bh0, acc[j], 0, 0, 0);
        acc[j] = __builtin_amdgcn_mfma_f32_16x16x32_bf16(w1h[0], bl0, acc[j], 0, 0, 0);
        acc[j] = __builtin_amdgcn_mfma_f32_16x16x32_bf16(w1l[0], bh0, acc[j], 0, 0, 0);
        acc[j] = __builtin_amdgcn_mfma_f32_16x16x32_bf16(w1h[1], bh1, acc[j], 0, 0, 0);
        acc[j] = __builtin_amdgcn_mfma_f32_16x16x32_bf16(w1h[1], bl1, acc[j], 0, 0, 0);
        acc[j] = __builtin_amdgcn_mfma_f32_16x16x32_bf16(w1l[1], bh1, acc[j], 0, 0, 0);
    }
#pragma unroll
    for (int j = 0; j < 8; ++j) {
        const int px = 16 * j + li;
        const int idx = ((go ^ l7) << 3) + co;
        unsigned h0 = f2bf(fmaxf(acc[j][0] + b1v[0], 0.f));
        unsigned h1 = f2bf(fmaxf(acc[j][1] + b1v[1], 0.f));
        unsigned h2 = f2bf(fmaxf(acc[j][2] + b1v[2], 0.f));
        unsigned h3 = f2bf(fmaxf(acc[j][3] + b1v[3], 0.f));
        *(unsigned*)&hsh[px][idx]     = h0 | (h1 << 16);
        *(unsigned*)&hsh[px][idx + 2] = h2 | (h3 << 16);
    }
    __syncthreads();

    // ---- GEMM2: Z = W2 * H + b2 (split W x bf16 H) ; out = Y * sigmoid(Z) ----
#pragma unroll
    for (int j = 0; j < 8; ++j) acc[j] = (f32x4){0.f, 0.f, 0.f, 0.f};
#pragma unroll
    for (int j = 0; j < 8; ++j) {
        const int row = 16 * j + li;
        bf8 bh0 = *(const bf8*)&hsh[row][sg0];
        bf8 bh1 = *(const bf8*)&hsh[row][sg1];
        acc[j] = __builtin_amdgcn_mfma_f32_16x16x32_bf16(w2h[0], bh0, acc[j], 0, 0, 0);
        acc[j] = __builtin_amdgcn_mfma_f32_16x16x32_bf16(w2l[0], bh0, acc[j], 0, 0, 0);
        acc[j] = __builtin_amdgcn_mfma_f32_16x16x32_bf16(w2h[1], bh1, acc[j], 0, 0, 0);
        acc[j] = __builtin_amdgcn_mfma_f32_16x16x32_bf16(w2l[1], bh1, acc[j], 0, 0, 0);
    }
    float* outB = out + (size_t)b * 64 * 262144 + (size_t)(hb * 8) * 512 + wt * 16 + li;
#pragma unroll
    for (int j = 0; j < 8; ++j) {
        const int px = 16 * j + li;
        const int idx = ((go ^ l7) << 3) + co;
        unsigned a0 = *(const unsigned*)&ysh[px][idx];
        unsigned a1 = *(const unsigned*)&ysh[px][idx + 2];
        unsigned c0 = *(const unsigned*)&ysl[px][idx];
        unsigned c1 = *(const unsigned*)&ysl[px][idx + 2];
        float yy[4];
        yy[0] = bf2f(a0 & 0xFFFFu) + bf2f(c0 & 0xFFFFu);
        yy[1] = bf2f(a0 >> 16)     + bf2f(c0 >> 16);
        yy[2] = bf2f(a1 & 0xFFFFu) + bf2f(c1 & 0xFFFFu);
        yy[3] = bf2f(a1 >> 16)     + bf2f(c1 >> 16);
#pragma unroll
        for (int r = 0; r < 4; ++r) {
            float z = acc[j][r] + b2v[r];
            float g = __builtin_amdgcn_rcpf(1.f + __expf(-z));
            outB[(size_t)(o0 + r) * 262144 + j * 512] = yy[r] * g;
        }
    }
}

extern "C" void kernel_launch(void* const* d_in, const int* in_sizes, int n_in,
                              void* d_out, int out_size, void* d_ws, size_t ws_size,
                              hipStream_t stream) {
    (void)in_sizes; (void)n_in; (void)out_size; (void)d_ws; (void)ws_size;
    const float* x   = (const float*)d_in[0];
    const float* twm = (const float*)d_in[1];
    const float* w1  = (const float*)d_in[2];
    const float* b1  = (const float*)d_in[3];
    const float* w2  = (const float*)d_in[4];
    const float* b2  = (const float*)d_in[5];
    float* out = (float*)d_out;

    avif_mfma3<<<dim3(4 * 64 * 32), dim3(256), 0, stream>>>(x, twm, w1, b1, w2, b2, out);
}

// Round 5
// 216.936 us; speedup vs baseline: 3.7292x; 3.7292x over previous
//
#include <hip/hip_runtime.h>

typedef float f4 __attribute__((ext_vector_type(4)));
typedef __attribute__((ext_vector_type(4))) float f32x4;
typedef __attribute__((ext_vector_type(8))) short bf8;

__device__ __forceinline__ ushort f2bf(float f) {
    union { float f; unsigned u; } v; v.f = f;
    return (ushort)((v.u + 0x7FFFu + ((v.u >> 16) & 1u)) >> 16);
}
__device__ __forceinline__ float bf2f(unsigned hu16) {
    union { unsigned u; float f; } v; v.u = hu16 << 16;
    return v.f;
}
__device__ __forceinline__ void split2(float v, ushort& hi, ushort& lo) {
    hi = f2bf(v);
    lo = f2bf(v - bf2f((unsigned)hi));
}

__global__ __launch_bounds__(256, 3)
void avif_mfma5(const float* __restrict__ x, const float* __restrict__ twm,
                const float* __restrict__ w1, const float* __restrict__ b1,
                const float* __restrict__ w2, const float* __restrict__ b2,
                float* __restrict__ out)
{
    // XOR-swizzled planes (granule = 8 ushorts = 16B):
    // element (px, c) -> row px, ushort index ((c>>3)^(px&7))*8 + (c&7)
    __shared__ ushort ysh[128][64];   // Y hi
    __shared__ ushort ysl[128][64];   // Y lo
    __shared__ ushort hsh[128][64];   // H hi (48 KB total -> 3 blocks/CU)

    const int t = threadIdx.x;
    const int bid = blockIdx.x;
    // XCD-friendly decode
    const int b3 = (bid >> 3) & 1;
    const int u  = ((bid >> 4) << 3) | (bid & 7);
    const int wt = ((u & 15) << 1) | b3;   // 0..31
    const int hb = (u >> 4) & 63;          // 0..63
    const int b  = u >> 10;                // 0..3

    const int wv   = t >> 6;
    const int lane = t & 63;
    const int li   = lane & 15;
    const int lg   = lane >> 4;
    const int l7   = li & 7;

    // ---- phase 1: lane pair shares one (c,blk); both compute M, each writes
    // 4 of 8 output rows. Live set kept ~100 regs (no scratch spill).
    {
        const int pid = t >> 1;          // 0..127
        const int h2  = t & 1;           // output-row half
        const int c   = pid & 63, blk = pid >> 6;
        const float* xB = x + ((size_t)(b * 64 + c) * 512 + hb * 8) * 512
                            + wt * 16 + blk * 8;
        const float* tB = twm + c * 64;

        float M[8][8];
        // stage 1: M = P * T^T, accumulated over k-halves (j=0..3, then 4..7)
        {
            f4 Ph[8];
#pragma unroll
            for (int i = 0; i < 8; ++i) Ph[i] = *(const f4*)(xB + i * 512);
#pragma unroll
            for (int q = 0; q < 8; ++q) {
                f4 Th = *(const f4*)(tB + q * 8);
#pragma unroll
                for (int i = 0; i < 8; ++i) {
                    float s = Ph[i][0] * Th[0];
                    s = fmaf(Ph[i][1], Th[1], s);
                    s = fmaf(Ph[i][2], Th[2], s);
                    s = fmaf(Ph[i][3], Th[3], s);
                    M[i][q] = s;
                }
            }
#pragma unroll
            for (int i = 0; i < 8; ++i) Ph[i] = *(const f4*)(xB + i * 512 + 4);
#pragma unroll
            for (int q = 0; q < 8; ++q) {
                f4 Th = *(const f4*)(tB + q * 8 + 4);
#pragma unroll
                for (int i = 0; i < 8; ++i) {
                    float s = M[i][q];
                    s = fmaf(Ph[i][0], Th[0], s);
                    s = fmaf(Ph[i][1], Th[1], s);
                    s = fmaf(Ph[i][2], Th[2], s);
                    s = fmaf(Ph[i][3], Th[3], s);
                    M[i][q] = s;
                }
            }
        }
        // stage 2: Y rows p = 4*h2 .. 4*h2+3 ; T row reloaded per p (L2-hot)
        const int cg = c >> 3, c7 = c & 7;
#pragma unroll
        for (int pp = 0; pp < 4; ++pp) {
            const int p = 4 * h2 + pp;
            f4 a = *(const f4*)(tB + p * 8);
            f4 d = *(const f4*)(tB + p * 8 + 4);
            const int px0 = p * 16 + blk * 8;
#pragma unroll
            for (int q = 0; q < 8; ++q) {
                float s = a[0] * M[0][q];
                s = fmaf(a[1], M[1][q], s);
                s = fmaf(a[2], M[2][q], s);
                s = fmaf(a[3], M[3][q], s);
                s = fmaf(d[0], M[4][q], s);
                s = fmaf(d[1], M[5][q], s);
                s = fmaf(d[2], M[6][q], s);
                s = fmaf(d[3], M[7][q], s);
                ushort hi, lo; split2(s, hi, lo);
                const int idx = ((cg ^ q) << 3) | c7;   // px&7 == q
                ysh[px0 + q][idx] = hi;
                ysl[px0 + q][idx] = lo;
            }
        }
    }

    // ---- W fragments (hi+lo) in registers; each wave needs only its 16 rows ----
    bf8 w1h[2], w1l[2], w2h[2], w2l[2];
    {
        const float* p1 = w1 + (16 * wv + li) * 64 + lg * 8;
        const float* p2 = w2 + (16 * wv + li) * 64 + lg * 8;
#pragma unroll
        for (int kk = 0; kk < 2; ++kk) {
            f4 a = *(const f4*)(p1 + kk * 32);
            f4 d = *(const f4*)(p1 + kk * 32 + 4);
            bf8 fh, fl; ushort hi, lo;
#pragma unroll
            for (int q = 0; q < 4; ++q) {
                split2(a[q], hi, lo); fh[q] = (short)hi; fl[q] = (short)lo;
                split2(d[q], hi, lo); fh[4 + q] = (short)hi; fl[4 + q] = (short)lo;
            }
            w1h[kk] = fh; w1l[kk] = fl;
            a = *(const f4*)(p2 + kk * 32);
            d = *(const f4*)(p2 + kk * 32 + 4);
#pragma unroll
            for (int q = 0; q < 4; ++q) {
                split2(a[q], hi, lo); fh[q] = (short)hi; fl[q] = (short)lo;
                split2(d[q], hi, lo); fh[4 + q] = (short)hi; fl[4 + q] = (short)lo;
            }
            w2h[kk] = fh; w2l[kk] = fl;
        }
    }
    const int o0 = 16 * wv + 4 * lg;
    const f4 b1v = *(const f4*)(b1 + o0);
    const f4 b2v = *(const f4*)(b2 + o0);
    const int sg0 = ((lg)     ^ l7) << 3;
    const int sg1 = ((4 + lg) ^ l7) << 3;
    const int go  = o0 >> 3, co = 4 * (lg & 1);

    __syncthreads();

    // ---- GEMM1: H = relu(W1 * Y + b1), split x split (3 MFMA per K=32) ----
    f32x4 acc[8];
#pragma unroll
    for (int j = 0; j < 8; ++j) acc[j] = (f32x4){0.f, 0.f, 0.f, 0.f};
#pragma unroll
    for (int j = 0; j < 8; ++j) {
        const int row = 16 * j + li;
        bf8 bh0 = *(const bf8*)&ysh[row][sg0];
        bf8 bl0 = *(const bf8*)&ysl[row][sg0];
        bf8 bh1 = *(const bf8*)&ysh[row][sg1];
        bf8 bl1 = *(const bf8*)&ysl[row][sg1];
        acc[j] = __builtin_amdgcn_mfma_f32_16x16x32_bf16(w1h[0], bh0, acc[j], 0, 0, 0);
        acc[j] = __builtin_amdgcn_mfma_f32_16x16x32_bf16(w1h[0], bl0, acc[j], 0, 0, 0);
        acc[j] = __builtin_amdgcn_mfma_f32_16x16x32_bf16(w1l[0], bh0, acc[j], 0, 0, 0);
        acc[j] = __builtin_amdgcn_mfma_f32_16x16x32_bf16(w1h[1], bh1, acc[j], 0, 0, 0);
        acc[j] = __builtin_amdgcn_mfma_f32_16x16x32_bf16(w1h[1], bl1, acc[j], 0, 0, 0);
        acc[j] = __builtin_amdgcn_mfma_f32_16x16x32_bf16(w1l[1], bh1, acc[j], 0, 0, 0);
    }
#pragma unroll
    for (int j = 0; j < 8; ++j) {
        const int px = 16 * j + li;
        const int idx = ((go ^ l7) << 3) + co;
        unsigned h0 = f2bf(fmaxf(acc[j][0] + b1v[0], 0.f));
        unsigned h1 = f2bf(fmaxf(acc[j][1] + b1v[1], 0.f));
        unsigned h2 = f2bf(fmaxf(acc[j][2] + b1v[2], 0.f));
        unsigned h3 = f2bf(fmaxf(acc[j][3] + b1v[3], 0.f));
        *(unsigned*)&hsh[px][idx]     = h0 | (h1 << 16);
        *(unsigned*)&hsh[px][idx + 2] = h2 | (h3 << 16);
    }
    __syncthreads();

    // ---- GEMM2: Z = W2 * H + b2 (split W x bf16 H) ; out = Y * sigmoid(Z) ----
#pragma unroll
    for (int j = 0; j < 8; ++j) acc[j] = (f32x4){0.f, 0.f, 0.f, 0.f};
#pragma unroll
    for (int j = 0; j < 8; ++j) {
        const int row = 16 * j + li;
        bf8 bh0 = *(const bf8*)&hsh[row][sg0];
        bf8 bh1 = *(const bf8*)&hsh[row][sg1];
        acc[j] = __builtin_amdgcn_mfma_f32_16x16x32_bf16(w2h[0], bh0, acc[j], 0, 0, 0);
        acc[j] = __builtin_amdgcn_mfma_f32_16x16x32_bf16(w2l[0], bh0, acc[j], 0, 0, 0);
        acc[j] = __builtin_amdgcn_mfma_f32_16x16x32_bf16(w2h[1], bh1, acc[j], 0, 0, 0);
        acc[j] = __builtin_amdgcn_mfma_f32_16x16x32_bf16(w2l[1], bh1, acc[j], 0, 0, 0);
    }
    float* outB = out + (size_t)b * 64 * 262144 + (size_t)(hb * 8) * 512 + wt * 16 + li;
#pragma unroll
    for (int j = 0; j < 8; ++j) {
        const int px = 16 * j + li;
        const int idx = ((go ^ l7) << 3) + co;
        unsigned a0 = *(const unsigned*)&ysh[px][idx];
        unsigned a1 = *(const unsigned*)&ysh[px][idx + 2];
        unsigned c0 = *(const unsigned*)&ysl[px][idx];
        unsigned c1 = *(const unsigned*)&ysl[px][idx + 2];
        float yy[4];
        yy[0] = bf2f(a0 & 0xFFFFu) + bf2f(c0 & 0xFFFFu);
        yy[1] = bf2f(a0 >> 16)     + bf2f(c0 >> 16);
        yy[2] = bf2f(a1 & 0xFFFFu) + bf2f(c1 & 0xFFFFu);
        yy[3] = bf2f(a1 >> 16)     + bf2f(c1 >> 16);
#pragma unroll
        for (int r = 0; r < 4; ++r) {
            float z = acc[j][r] + b2v[r];
            float g = __builtin_amdgcn_rcpf(1.f + __expf(-z));
            outB[(size_t)(o0 + r) * 262144 + j * 512] = yy[r] * g;
        }
    }
}

extern "C" void kernel_launch(void* const* d_in, const int* in_sizes, int n_in,
                              void* d_out, int out_size, void* d_ws, size_t ws_size,
                              hipStream_t stream) {
    (void)in_sizes; (void)n_in; (void)out_size; (void)d_ws; (void)ws_size;
    const float* x   = (const float*)d_in[0];
    const float* twm = (const float*)d_in[1];
    const float* w1  = (const float*)d_in[2];
    const float* b1  = (const float*)d_in[3];
    const float* w2  = (const float*)d_in[4];
    const float* b2  = (const float*)d_in[5];
    float* out = (float*)d_out;

    avif_mfma5<<<dim3(4 * 64 * 32), dim3(256), 0, stream>>>(x, twm, w1, b1, w2, b2, out);
}